// Round 9
// baseline (305.933 us; speedup 1.0000x reference)
//
#include <hip/hip_runtime.h>

// PyFlowODE: Heun integration of dx/dt = (x - q(x,t))/t with Nadaraya-Watson
// Gaussian RBF retrieval. N=2048 queries (d=8), B=4096 bank, T=16 steps.
//
// Round-6 structure (resubmitted; broker timeouts, never benched):
//  - 256 blocks x 1024 threads (16 waves) -> 2048 thr/CU = 4 waves/SIMD
//    (round-2's 512-thr block gave only 2 waves/SIMD; VALUBusy stuck at 70%).
//  - LDS: x0 staged once (128 KB split lo/hi float4, conflict-free
//    ds_read_b128) + 1.5 KB merge buffer. Still 1 block/CU.
//  - 8 queries/block; each query PAIR owned by 4 waves; each wave covers a
//    QUARTER bank (16 entries/lane) for its 2 queries; 4-way merge via LDS.
//  - Softmax tracked as running MIN of ||z||^2 (zz-domain): weight
//    w = exp2(fma(c0, zz, t0)); deferred rescale (40 log2-unit headroom).
//  - t=1 eval: alpha=0 -> uniform weights -> q = mean(x0) exactly; eval deleted.

#define NQ     2048
#define NB     4096
#define TSTEPS 16
#define BLOCK  1024
#define NWAVE  16

#if defined(__has_builtin)
#if __has_builtin(__builtin_amdgcn_exp2f)
#define EXP2(x) __builtin_amdgcn_exp2f(x)
#endif
#endif
#ifndef EXP2
#define EXP2(x) exp2f(x)
#endif

// Evaluate G(x, t) for this wave's TWO queries (xq wave-uniform per query).
// Wave covers bank quarter `quad`; partials merged across the 4 waves of
// the query-pair group via mrg.
__device__ __forceinline__ void eval_pair(
        const float4* __restrict__ lds_lo,
        const float4* __restrict__ lds_hi,
        float (*mrg)[2][12],
        const float (&xq)[2][8], float t, int lane, int quad, int w,
        float (&Gout)[2][8])
{
    const float c0      = -0.72134752044448170f / (t * t);   // -0.5*log2(e)/t^2
    const float alpha   = 1.0f - t;
    const float thr_off = 40.0f / c0;                        // negative
    float mz[2] = {3.0e38f, 3.0e38f};   // running min of zz (per lane)
    float th[2] = {3.0e38f, 3.0e38f};   // rescale trigger: zz < th
    float t0[2] = {0.0f, 0.0f};         // -c0*mz (valid after first rescale)
    float s[2]  = {0.0f, 0.0f};
    float q[2][8];
#pragma unroll
    for (int qq = 0; qq < 2; ++qq)
#pragma unroll
        for (int j = 0; j < 8; ++j) q[qq][j] = 0.0f;

    const int b0 = lane + quad * 1024;   // quarter bank: 16 entries/lane

#pragma unroll
    for (int g = 0; g < 4; ++g) {
        float4 lo[4], hi[4];
        float  zz[2][4];
#pragma unroll
        for (int e = 0; e < 4; ++e) {
            const int b = b0 + g * 256 + e * 64;   // lanes contiguous: conflict-free
            lo[e] = lds_lo[b];
            hi[e] = lds_hi[b];
#pragma unroll
            for (int qq = 0; qq < 2; ++qq) {
                float z, acc;
                z = fmaf(-alpha, lo[e].x, xq[qq][0]); acc = z * z;
                z = fmaf(-alpha, lo[e].y, xq[qq][1]); acc = fmaf(z, z, acc);
                z = fmaf(-alpha, lo[e].z, xq[qq][2]); acc = fmaf(z, z, acc);
                z = fmaf(-alpha, lo[e].w, xq[qq][3]); acc = fmaf(z, z, acc);
                z = fmaf(-alpha, hi[e].x, xq[qq][4]); acc = fmaf(z, z, acc);
                z = fmaf(-alpha, hi[e].y, xq[qq][5]); acc = fmaf(z, z, acc);
                z = fmaf(-alpha, hi[e].z, xq[qq][6]); acc = fmaf(z, z, acc);
                z = fmaf(-alpha, hi[e].w, xq[qq][7]); acc = fmaf(z, z, acc);
                zz[qq][e] = acc;
            }
        }
#pragma unroll
        for (int qq = 0; qq < 2; ++qq) {
            const float bz = fminf(fminf(zz[qq][0], zz[qq][1]),
                                   fminf(zz[qq][2], zz[qq][3]));
            if (__any(bz < th[qq])) {      // wave-uniform; always taken at g=0
                const float mzn = fminf(mz[qq], bz);
                const float c = EXP2(c0 * (mz[qq] - mzn));  // first time: exp2(-inf)=0
                s[qq] *= c;
#pragma unroll
                for (int j = 0; j < 8; ++j) q[qq][j] *= c;
                mz[qq] = mzn;
                th[qq] = mzn + thr_off;
                t0[qq] = -c0 * mzn;
            }
#pragma unroll
            for (int e = 0; e < 4; ++e) {
                const float wgt = EXP2(fmaf(c0, zz[qq][e], t0[qq]));  // underflow->0 ok
                s[qq] += wgt;
                q[qq][0] = fmaf(wgt, lo[e].x, q[qq][0]);
                q[qq][1] = fmaf(wgt, lo[e].y, q[qq][1]);
                q[qq][2] = fmaf(wgt, lo[e].z, q[qq][2]);
                q[qq][3] = fmaf(wgt, lo[e].w, q[qq][3]);
                q[qq][4] = fmaf(wgt, hi[e].x, q[qq][4]);
                q[qq][5] = fmaf(wgt, hi[e].y, q[qq][5]);
                q[qq][6] = fmaf(wgt, hi[e].z, q[qq][6]);
                q[qq][7] = fmaf(wgt, hi[e].w, q[qq][7]);
            }
        }
    }

    // ---- per-wave cross-lane reduce (butterfly; all lanes get wave totals) ----
#pragma unroll
    for (int qq = 0; qq < 2; ++qq) {
        float mw = mz[qq];
#pragma unroll
        for (int off = 32; off >= 1; off >>= 1)
            mw = fminf(mw, __shfl_xor(mw, off));
        const float c = EXP2(c0 * (mz[qq] - mw));   // mz>=mw -> c<=1
        s[qq] *= c;
#pragma unroll
        for (int j = 0; j < 8; ++j) q[qq][j] *= c;
        mz[qq] = mw;
#pragma unroll
        for (int off = 32; off >= 1; off >>= 1) {
            s[qq] += __shfl_xor(s[qq], off);
#pragma unroll
            for (int j = 0; j < 8; ++j) q[qq][j] += __shfl_xor(q[qq][j], off);
        }
    }

    // ---- cross-wave 4-way merge via LDS (waves g0..g0+3 share the queries) ----
    if (lane == 0) {
#pragma unroll
        for (int qq = 0; qq < 2; ++qq) {
            float* p = mrg[w][qq];
            p[0] = mz[qq];
            p[1] = s[qq];
#pragma unroll
            for (int j = 0; j < 8; ++j) p[2 + j] = q[qq][j];
        }
    }
    __syncthreads();
    const int g0 = w & ~3;               // first wave of this query-group
    const float invT = 1.0f / t;
#pragma unroll
    for (int qq = 0; qq < 2; ++qq) {
        // identical slot order in all 4 waves -> bit-identical results
        float mzk[4], sk[4];
#pragma unroll
        for (int k = 0; k < 4; ++k) {
            mzk[k] = mrg[g0 + k][qq][0];
            sk[k]  = mrg[g0 + k][qq][1];
        }
        const float M = fminf(fminf(mzk[0], mzk[1]), fminf(mzk[2], mzk[3]));
        float ck[4];
        float S = 0.0f;
#pragma unroll
        for (int k = 0; k < 4; ++k) {
            ck[k] = EXP2(c0 * (mzk[k] - M));
            S = fmaf(ck[k], sk[k], S);
        }
        const float invS = 1.0f / S;
#pragma unroll
        for (int j = 0; j < 8; ++j) {
            float Q = 0.0f;
#pragma unroll
            for (int k = 0; k < 4; ++k)
                Q = fmaf(ck[k], mrg[g0 + k][qq][2 + j], Q);
            Gout[qq][j] = fmaf(-Q, invS, xq[qq][j]) * invT;
        }
    }
    __syncthreads();   // protect mrg before next eval's write
}

__global__ __launch_bounds__(BLOCK, 4) void flow_ode_kernel(
        const float* __restrict__ x1,
        const float* __restrict__ x0,
        float* __restrict__ out)
{
    __shared__ float4 lds_lo[NB];          // x0[b][0:4]
    __shared__ float4 lds_hi[NB];          // x0[b][4:8]
    __shared__ float  mrg[NWAVE][2][12];   // per-wave partials / staging wavesums

    const int tid  = threadIdx.x;
    const int w    = tid >> 6;
    const int lane = tid & 63;

    // ---- stage x0 (128 KB) + per-thread partial column sums for mean ----
    float sm[8];
#pragma unroll
    for (int j = 0; j < 8; ++j) sm[j] = 0.0f;
#pragma unroll
    for (int i = 0; i < NB / BLOCK; ++i) {
        const int b = tid + i * BLOCK;
        const float4* p = reinterpret_cast<const float4*>(x0) + 2 * b;
        const float4 lo = p[0], hi = p[1];
        lds_lo[b] = lo;
        lds_hi[b] = hi;
        sm[0] += lo.x; sm[1] += lo.y; sm[2] += lo.z; sm[3] += lo.w;
        sm[4] += hi.x; sm[5] += hi.y; sm[6] += hi.z; sm[7] += hi.w;
    }
#pragma unroll
    for (int off = 32; off >= 1; off >>= 1)
#pragma unroll
        for (int j = 0; j < 8; ++j) sm[j] += __shfl_xor(sm[j], off);
    if (lane == 0) {
#pragma unroll
        for (int j = 0; j < 8; ++j) mrg[w][0][j] = sm[j];
    }
    __syncthreads();
    float mean[8];
#pragma unroll
    for (int j = 0; j < 8; ++j) {
        float acc = 0.0f;
#pragma unroll
        for (int wv = 0; wv < NWAVE; ++wv) acc += mrg[wv][0][j];
        mean[j] = acc * (1.0f / (float)NB);
    }
    __syncthreads();

    // ---- wave -> query-pair assignment: group of 4 waves per 2 queries ----
    const int quad  = w & 3;            // bank quarter
    const int grp   = w >> 2;           // query-pair group, 0..3
    const int qbase = blockIdx.x * 8 + grp * 2;

    float xt[2][8], G1[2][8];
#pragma unroll
    for (int qq = 0; qq < 2; ++qq) {
        const float4* p = reinterpret_cast<const float4*>(x1) + 2 * (qbase + qq);
        const float4 a = p[0], b4 = p[1];
        xt[qq][0] = a.x;  xt[qq][1] = a.y;  xt[qq][2] = a.z;  xt[qq][3] = a.w;
        xt[qq][4] = b4.x; xt[qq][5] = b4.y; xt[qq][6] = b4.z; xt[qq][7] = b4.w;
    }
    // G1 at t=1: alpha=0 -> uniform weights -> q = mean(x0) exactly
#pragma unroll
    for (int qq = 0; qq < 2; ++qq)
#pragma unroll
        for (int j = 0; j < 8; ++j) G1[qq][j] = xt[qq][j] - mean[j];

    const float hstep = 0.0625f;   // 1/16
    for (int i = 1; i < TSTEPS; ++i) {
        const float t = 1.0f - hstep * (float)i;   // exact in f32
        float xe[2][8], G2[2][8];
#pragma unroll
        for (int qq = 0; qq < 2; ++qq)
#pragma unroll
            for (int j = 0; j < 8; ++j)
                xe[qq][j] = fmaf(-hstep, G1[qq][j], xt[qq][j]);   // Euler predictor
        eval_pair(lds_lo, lds_hi, mrg, xe, t, lane, quad, w, G2);
#pragma unroll
        for (int qq = 0; qq < 2; ++qq)
#pragma unroll
            for (int j = 0; j < 8; ++j) {
                xt[qq][j] = fmaf(-0.03125f, G1[qq][j] + G2[qq][j], xt[qq][j]);
                G1[qq][j] = G2[qq][j];
            }
    }

    if (quad == 0 && lane == 0) {
#pragma unroll
        for (int qq = 0; qq < 2; ++qq) {
            float4 a, b4;
            a.x  = xt[qq][0]; a.y  = xt[qq][1]; a.z  = xt[qq][2]; a.w  = xt[qq][3];
            b4.x = xt[qq][4]; b4.y = xt[qq][5]; b4.z = xt[qq][6]; b4.w = xt[qq][7];
            float4* o = reinterpret_cast<float4*>(out + (qbase + qq) * 8);
            o[0] = a;
            o[1] = b4;
        }
    }
}

extern "C" void kernel_launch(void* const* d_in, const int* in_sizes, int n_in,
                              void* d_out, int out_size, void* d_ws, size_t ws_size,
                              hipStream_t stream) {
    const float* x1 = (const float*)d_in[0];   // (2048, 8)
    const float* x0 = (const float*)d_in[1];   // (4096, 8)
    float* out = (float*)d_out;                // (2048, 8)

    flow_ode_kernel<<<NQ / 8, BLOCK, 0, stream>>>(x1, x0, out);
}

// Round 10
// 176.507 us; speedup vs baseline: 1.7333x; 1.7333x over previous
//
#include <hip/hip_runtime.h>

// PyFlowODE: Heun integration of dx/dt = (x - q(x,t))/t with Nadaraya-Watson
// Gaussian RBF retrieval. N=2048 queries (d=8), B=4096 bank, T=16 steps.
//
// Round-10 structure:
//  - 256 blocks x 1024 threads (16 waves) = 4 waves/SIMD (occupancy lever,
//    proven resident in round 9: OccupancyPercent 45.5).
//  - ROUND-9 LESSON: __launch_bounds__(1024,4) + 2-queries/wave clamped VGPR
//    to 64 -> 885 MB scratch spill traffic -> 270 us. Fix: ONE query per
//    wave (~95 VGPR) and __launch_bounds__(1024) only (block size alone
//    caps VGPR at 128; no waves/EU hint).
//  - 8 queries/block; each query owned by 2 waves (w>>1 = query, w&1 = bank
//    half, 16 entries... 32 entries/lane); 2-way LDS merge per eval.
//  - LDS: x0 staged once (128 KB split lo/hi float4, conflict-free
//    ds_read_b128) + merge buffer. 1 block/CU (LDS-pinned).
//  - Softmax: running MIN of ||z||^2, weight = exp2(fma(c0, zz, t0)),
//    deferred rescale (40 log2-unit headroom), wave-uniform trigger.
//  - t=1 eval: alpha=0 -> uniform weights -> q = mean(x0) exactly; deleted.

#define NQ     2048
#define NB     4096
#define TSTEPS 16
#define BLOCK  1024
#define NWAVE  16

#if defined(__has_builtin)
#if __has_builtin(__builtin_amdgcn_exp2f)
#define EXP2(x) __builtin_amdgcn_exp2f(x)
#endif
#endif
#ifndef EXP2
#define EXP2(x) exp2f(x)
#endif

// Evaluate G(x, t) for this wave's ONE query (xq wave-uniform).
// Wave covers bank half h; partials merged with partner wave (w^1) via mrg.
__device__ __forceinline__ void eval_one(
        const float4* __restrict__ lds_lo,
        const float4* __restrict__ lds_hi,
        float (*mrg)[12],
        const float (&xq)[8], float t, int lane, int h, int w,
        float (&Gout)[8])
{
    const float c0      = -0.72134752044448170f / (t * t);   // -0.5*log2(e)/t^2
    const float alpha   = 1.0f - t;
    const float thr_off = 40.0f / c0;                        // negative
    float mz = 3.0e38f;   // running min of zz (per lane)
    float th = 3.0e38f;   // rescale trigger: zz < th
    float t0 = 0.0f;      // -c0*mz (valid after first rescale)
    float s  = 0.0f;
    float q[8];
#pragma unroll
    for (int j = 0; j < 8; ++j) q[j] = 0.0f;

    const int b0 = lane + h * 2048;     // half bank: 32 entries/lane

#pragma unroll
    for (int g = 0; g < 8; ++g) {
        float4 lo[4], hi[4];
        float  zz[4];
#pragma unroll
        for (int e = 0; e < 4; ++e) {
            const int b = b0 + g * 256 + e * 64;   // lanes contiguous: conflict-free
            lo[e] = lds_lo[b];
            hi[e] = lds_hi[b];
            float z, acc;
            z = fmaf(-alpha, lo[e].x, xq[0]); acc = z * z;
            z = fmaf(-alpha, lo[e].y, xq[1]); acc = fmaf(z, z, acc);
            z = fmaf(-alpha, lo[e].z, xq[2]); acc = fmaf(z, z, acc);
            z = fmaf(-alpha, lo[e].w, xq[3]); acc = fmaf(z, z, acc);
            z = fmaf(-alpha, hi[e].x, xq[4]); acc = fmaf(z, z, acc);
            z = fmaf(-alpha, hi[e].y, xq[5]); acc = fmaf(z, z, acc);
            z = fmaf(-alpha, hi[e].z, xq[6]); acc = fmaf(z, z, acc);
            z = fmaf(-alpha, hi[e].w, xq[7]); acc = fmaf(z, z, acc);
            zz[e] = acc;
        }
        const float bz = fminf(fminf(zz[0], zz[1]), fminf(zz[2], zz[3]));
        if (__any(bz < th)) {          // wave-uniform; always taken at g=0
            const float mzn = fminf(mz, bz);
            const float c = EXP2(c0 * (mz - mzn));   // first time: exp2(-inf)=0
            s *= c;
#pragma unroll
            for (int j = 0; j < 8; ++j) q[j] *= c;
            mz = mzn;
            th = mzn + thr_off;
            t0 = -c0 * mzn;
        }
#pragma unroll
        for (int e = 0; e < 4; ++e) {
            const float wgt = EXP2(fmaf(c0, zz[e], t0));   // underflow->0 ok
            s += wgt;
            q[0] = fmaf(wgt, lo[e].x, q[0]);
            q[1] = fmaf(wgt, lo[e].y, q[1]);
            q[2] = fmaf(wgt, lo[e].z, q[2]);
            q[3] = fmaf(wgt, lo[e].w, q[3]);
            q[4] = fmaf(wgt, hi[e].x, q[4]);
            q[5] = fmaf(wgt, hi[e].y, q[5]);
            q[6] = fmaf(wgt, hi[e].z, q[6]);
            q[7] = fmaf(wgt, hi[e].w, q[7]);
        }
    }

    // ---- per-wave cross-lane reduce (butterfly; all lanes get wave totals) ----
    float mw = mz;
#pragma unroll
    for (int off = 32; off >= 1; off >>= 1)
        mw = fminf(mw, __shfl_xor(mw, off));
    const float cw = EXP2(c0 * (mz - mw));   // mz>=mw -> cw<=1
    s *= cw;
#pragma unroll
    for (int j = 0; j < 8; ++j) q[j] *= cw;
    mz = mw;
#pragma unroll
    for (int off = 32; off >= 1; off >>= 1) {
        s += __shfl_xor(s, off);
#pragma unroll
        for (int j = 0; j < 8; ++j) q[j] += __shfl_xor(q[j], off);
    }

    // ---- cross-wave (pair) merge via LDS ----
    if (lane == 0) {
        float* p = mrg[w];
        p[0] = mz;
        p[1] = s;
#pragma unroll
        for (int j = 0; j < 8; ++j) p[2 + j] = q[j];
    }
    __syncthreads();
    const float* p = mrg[w ^ 1];
    const float mzb = p[0], sb = p[1];
    const float M    = fminf(mz, mzb);
    const float ca   = EXP2(c0 * (mz  - M));
    const float cb   = EXP2(c0 * (mzb - M));
    const float S    = ca * s + cb * sb;    // commutative: both waves identical
    const float invS = 1.0f / S;
    const float invT = 1.0f / t;
#pragma unroll
    for (int j = 0; j < 8; ++j) {
        const float Q = ca * q[j] + cb * p[2 + j];
        Gout[j] = fmaf(-Q, invS, xq[j]) * invT;
    }
    __syncthreads();   // protect mrg before next eval's write
}

__global__ __launch_bounds__(BLOCK) void flow_ode_kernel(
        const float* __restrict__ x1,
        const float* __restrict__ x0,
        float* __restrict__ out)
{
    __shared__ float4 lds_lo[NB];       // x0[b][0:4]
    __shared__ float4 lds_hi[NB];       // x0[b][4:8]
    __shared__ float  mrg[NWAVE][12];   // per-wave partials / staging wavesums

    const int tid  = threadIdx.x;
    const int w    = tid >> 6;
    const int lane = tid & 63;

    // ---- stage x0 (128 KB) + per-thread partial column sums for mean ----
    float sm[8];
#pragma unroll
    for (int j = 0; j < 8; ++j) sm[j] = 0.0f;
#pragma unroll
    for (int i = 0; i < NB / BLOCK; ++i) {
        const int b = tid + i * BLOCK;
        const float4* p = reinterpret_cast<const float4*>(x0) + 2 * b;
        const float4 lo = p[0], hi = p[1];
        lds_lo[b] = lo;
        lds_hi[b] = hi;
        sm[0] += lo.x; sm[1] += lo.y; sm[2] += lo.z; sm[3] += lo.w;
        sm[4] += hi.x; sm[5] += hi.y; sm[6] += hi.z; sm[7] += hi.w;
    }
#pragma unroll
    for (int off = 32; off >= 1; off >>= 1)
#pragma unroll
        for (int j = 0; j < 8; ++j) sm[j] += __shfl_xor(sm[j], off);
    if (lane == 0) {
#pragma unroll
        for (int j = 0; j < 8; ++j) mrg[w][j] = sm[j];
    }
    __syncthreads();
    float mean[8];
#pragma unroll
    for (int j = 0; j < 8; ++j) {
        float acc = 0.0f;
#pragma unroll
        for (int wv = 0; wv < NWAVE; ++wv) acc += mrg[wv][j];
        mean[j] = acc * (1.0f / (float)NB);
    }
    __syncthreads();

    // ---- wave -> query assignment: 2 waves per query (half bank each) ----
    const int h    = w & 1;             // bank half
    const int qidx = blockIdx.x * 8 + (w >> 1);

    float xt[8], G1[8];
    {
        const float4* p = reinterpret_cast<const float4*>(x1) + 2 * qidx;
        const float4 a = p[0], b4 = p[1];
        xt[0] = a.x;  xt[1] = a.y;  xt[2] = a.z;  xt[3] = a.w;
        xt[4] = b4.x; xt[5] = b4.y; xt[6] = b4.z; xt[7] = b4.w;
    }
    // G1 at t=1: alpha=0 -> uniform weights -> q = mean(x0) exactly
#pragma unroll
    for (int j = 0; j < 8; ++j) G1[j] = xt[j] - mean[j];

    const float hstep = 0.0625f;   // 1/16
    for (int i = 1; i < TSTEPS; ++i) {
        const float t = 1.0f - hstep * (float)i;   // exact in f32
        float xe[8], G2[8];
#pragma unroll
        for (int j = 0; j < 8; ++j)
            xe[j] = fmaf(-hstep, G1[j], xt[j]);    // Euler predictor
        eval_one(lds_lo, lds_hi, mrg, xe, t, lane, h, w, G2);
#pragma unroll
        for (int j = 0; j < 8; ++j) {
            xt[j] = fmaf(-0.03125f, G1[j] + G2[j], xt[j]);   // xt -= (G1+G2)*h/2
            G1[j] = G2[j];
        }
    }

    if (h == 0 && lane == 0) {
        float4 a, b4;
        a.x  = xt[0]; a.y  = xt[1]; a.z  = xt[2]; a.w  = xt[3];
        b4.x = xt[4]; b4.y = xt[5]; b4.z = xt[6]; b4.w = xt[7];
        float4* o = reinterpret_cast<float4*>(out + qidx * 8);
        o[0] = a;
        o[1] = b4;
    }
}

extern "C" void kernel_launch(void* const* d_in, const int* in_sizes, int n_in,
                              void* d_out, int out_size, void* d_ws, size_t ws_size,
                              hipStream_t stream) {
    const float* x1 = (const float*)d_in[0];   // (2048, 8)
    const float* x0 = (const float*)d_in[1];   // (4096, 8)
    float* out = (float*)d_out;                // (2048, 8)

    flow_ode_kernel<<<NQ / 8, BLOCK, 0, stream>>>(x1, x0, out);
}